// Round 2
// baseline (378.919 us; speedup 1.0000x reference)
//
#include <hip/hip_runtime.h>
#include <stdint.h>

typedef unsigned short ushort_t;
typedef __bf16 bf16x8 __attribute__((ext_vector_type(8)));
typedef float f32x4 __attribute__((ext_vector_type(4)));
typedef unsigned short ushort8 __attribute__((ext_vector_type(8)));
typedef __attribute__((address_space(1))) void GVoid;
typedef __attribute__((address_space(3))) void LVoid;

#define DEV static __device__ __forceinline__

DEV unsigned short f2bf(float f) {
    union { float f; unsigned int i; } v; v.f = f;
    unsigned int u = v.i;
    return (unsigned short)((u + 0x7fffu + ((u >> 16) & 1u)) >> 16);
}
DEV float bf2f(unsigned short u) {
    union { unsigned int i; float f; } v; v.i = ((unsigned int)u) << 16; return v.f;
}

// ---------------------------------------------------------------------------
// fp32 -> bf16 weight conversion (w1: 131072 elems, w2: 65536 elems)
// ---------------------------------------------------------------------------
__global__ __launch_bounds__(256) void cvt_kernel(
    const float* __restrict__ in, ushort_t* __restrict__ out, int n)
{
    int i = blockIdx.x * 256 + threadIdx.x;
    if (i < n) out[i] = f2bf(in[i]);
}

// ---------------------------------------------------------------------------
// 3-NN: one thread per query. xyz2[b] cached in LDS as float4{x,y,z,|p|^2}.
// d2 replicates the reference formula (qq + pp - 2*dot, non-FMA, same assoc
// order); strict < insertion keeps lowest-index on ties (top_k stable).
// ---------------------------------------------------------------------------
__global__ __launch_bounds__(256) void knn_kernel(
    const float* __restrict__ xyz1, const float* __restrict__ xyz2,
    int* __restrict__ idx_out, float* __restrict__ w_out)
{
    __shared__ float4 P[1024];
    const int b = blockIdx.y;
    const int tid = threadIdx.x;
    for (int s = tid; s < 1024; s += 256) {
        const float* p = xyz2 + ((size_t)b * 1024 + s) * 3;
        float x = p[0], y = p[1], z = p[2];
        float pp = __fadd_rn(__fadd_rn(__fmul_rn(x, x), __fmul_rn(y, y)), __fmul_rn(z, z));
        P[s] = make_float4(x, y, z, pp);
    }
    __syncthreads();
    const int n = blockIdx.x * 256 + tid;
    const float* q = xyz1 + ((size_t)b * 4096 + n) * 3;
    float qx = q[0], qy = q[1], qz = q[2];
    float qq = __fadd_rn(__fadd_rn(__fmul_rn(qx, qx), __fmul_rn(qy, qy)), __fmul_rn(qz, qz));
    float d0 = 1e30f, d1 = 1e30f, d2 = 1e30f;
    int i0 = 0, i1 = 0, i2 = 0;
    for (int s = 0; s < 1024; ++s) {
        float4 p = P[s];
        float dot = __fadd_rn(__fadd_rn(__fmul_rn(qx, p.x), __fmul_rn(qy, p.y)), __fmul_rn(qz, p.z));
        float d = __fsub_rn(__fadd_rn(qq, p.w), __fmul_rn(2.0f, dot));
        if (d < d2) {
            if (d < d1) {
                d2 = d1; i2 = i1;
                if (d < d0) { d1 = d0; i1 = i0; d0 = d; i0 = s; }
                else        { d1 = d;  i1 = s; }
            } else { d2 = d; i2 = s; }
        }
    }
    float r0 = 1.0f / (d0 + 1e-8f);
    float r1 = 1.0f / (d1 + 1e-8f);
    float r2 = 1.0f / (d2 + 1e-8f);
    float rs = __fadd_rn(__fadd_rn(r0, r1), r2);
    size_t o = ((size_t)b * 4096 + n) * 3;
    idx_out[o + 0] = i0; idx_out[o + 1] = i1; idx_out[o + 2] = i2;
    w_out[o + 0] = r0 / rs; w_out[o + 1] = r1 / rs; w_out[o + 2] = r2 / rs;
}

// ---------------------------------------------------------------------------
// GEMM1: y1[65536,256] = [points1 | interp] (65536x512, fp32 virtual) @ w1^T.
// BM=64, BN=256, BK=32, 4 waves x (64x64 tile = 4x4 mfma_16x16x32_bf16).
// A-staging: kc<8 -> points1 fp32 load + cvt + ds_write;
//            kc>=8 -> 3-NN interpolation computed on the fly (gather fp32
//            rows of points2, weighted sum, cvt, ds_write).
// B-staging: w1b bf16 via global_load_lds width=16.
// ---------------------------------------------------------------------------
__global__ __launch_bounds__(256) void gemm1_kernel(
    const float* __restrict__ p1, const float* __restrict__ points2,
    const int* __restrict__ idx, const float* __restrict__ wgt,
    const ushort_t* __restrict__ w1b, ushort_t* __restrict__ y)
{
    __shared__ ushort_t As[64 * 32];    // 4 KB
    __shared__ ushort_t Bs[256 * 32];   // 16 KB
    __shared__ int   sIdx[192];
    __shared__ float sWgt[192];
    const int tid = threadIdx.x;
    const int wave = tid >> 6, lane = tid & 63;
    const int fr = lane & 15, fq = lane >> 4;
    const int m0 = blockIdx.x * 64;
    const int sr = tid >> 2, sq = tid & 3;   // staging row (tid/4), col-group (tid%4)

    if (tid < 192) { sIdx[tid] = idx[(size_t)m0 * 3 + tid]; sWgt[tid] = wgt[(size_t)m0 * 3 + tid]; }

    const float* p2base = points2 + (size_t)(m0 >> 12) * (1024 * 256);

    f32x4 acc[4][4];
#pragma unroll
    for (int i = 0; i < 4; ++i)
#pragma unroll
        for (int j = 0; j < 4; ++j) acc[i][j] = f32x4{0.0f, 0.0f, 0.0f, 0.0f};

    for (int kc = 0; kc < 16; ++kc) {
        __syncthreads();
        // B tile 256x32 bf16 via async global->LDS (dest = uniform base + lane*16)
#pragma unroll
        for (int p = 0; p < 4; ++p) {
            const ushort_t* g = w1b + (size_t)(p * 64 + sr) * 512 + kc * 32 + sq * 8;
            __builtin_amdgcn_global_load_lds((GVoid*)g, (LVoid*)(Bs + p * 2048 + wave * 512), 16, 0, 0);
        }
        // A tile 64x32: thread t -> row t>>2, cols (t&3)*8 .. +8  (== As + t*8)
        {
            const int r = sr;              // row within tile
            const int c0 = sq * 8;         // col within 32-chunk
            float v[8];
            if (kc < 8) {
                const float4* g = (const float4*)(p1 + (size_t)(m0 + r) * 256 + kc * 32 + c0);
                float4 u0 = g[0], u1 = g[1];
                v[0] = u0.x; v[1] = u0.y; v[2] = u0.z; v[3] = u0.w;
                v[4] = u1.x; v[5] = u1.y; v[6] = u1.z; v[7] = u1.w;
            } else {
                const int ka = (kc - 8) * 32 + c0;
                int i0 = sIdx[r * 3 + 0], i1 = sIdx[r * 3 + 1], i2 = sIdx[r * 3 + 2];
                float w0 = sWgt[r * 3 + 0], w1 = sWgt[r * 3 + 1], w2 = sWgt[r * 3 + 2];
                const float4* g0 = (const float4*)(p2base + (size_t)i0 * 256 + ka);
                const float4* g1 = (const float4*)(p2base + (size_t)i1 * 256 + ka);
                const float4* g2 = (const float4*)(p2base + (size_t)i2 * 256 + ka);
                float4 a0 = g0[0], a1 = g0[1];
                float4 b0 = g1[0], b1 = g1[1];
                float4 c0v = g2[0], c1v = g2[1];
                v[0] = fmaf(w2, c0v.x, fmaf(w1, b0.x, __fmul_rn(w0, a0.x)));
                v[1] = fmaf(w2, c0v.y, fmaf(w1, b0.y, __fmul_rn(w0, a0.y)));
                v[2] = fmaf(w2, c0v.z, fmaf(w1, b0.z, __fmul_rn(w0, a0.z)));
                v[3] = fmaf(w2, c0v.w, fmaf(w1, b0.w, __fmul_rn(w0, a0.w)));
                v[4] = fmaf(w2, c1v.x, fmaf(w1, b1.x, __fmul_rn(w0, a1.x)));
                v[5] = fmaf(w2, c1v.y, fmaf(w1, b1.y, __fmul_rn(w0, a1.y)));
                v[6] = fmaf(w2, c1v.z, fmaf(w1, b1.z, __fmul_rn(w0, a1.z)));
                v[7] = fmaf(w2, c1v.w, fmaf(w1, b1.w, __fmul_rn(w0, a1.w)));
            }
            ushort8 hv;
#pragma unroll
            for (int j = 0; j < 8; ++j) hv[j] = f2bf(v[j]);
            *(ushort8*)(As + tid * 8) = hv;
        }
        __syncthreads();
        bf16x8 af[4], bfr[4];
#pragma unroll
        for (int i = 0; i < 4; ++i)
            af[i] = *(const bf16x8*)(As + (i * 16 + fr) * 32 + fq * 8);
#pragma unroll
        for (int j = 0; j < 4; ++j)
            bfr[j] = *(const bf16x8*)(Bs + (wave * 64 + j * 16 + fr) * 32 + fq * 8);
#pragma unroll
        for (int i = 0; i < 4; ++i)
#pragma unroll
            for (int j = 0; j < 4; ++j)
                acc[i][j] = __builtin_amdgcn_mfma_f32_16x16x32_bf16(af[i], bfr[j], acc[i][j], 0, 0, 0);
    }
#pragma unroll
    for (int i = 0; i < 4; ++i)
#pragma unroll
        for (int j = 0; j < 4; ++j)
#pragma unroll
            for (int r = 0; r < 4; ++r) {
                int row = m0 + i * 16 + fq * 4 + r;       // C/D: row=(lane>>4)*4+reg
                int col = wave * 64 + j * 16 + fr;        //      col=lane&15
                y[(size_t)row * 256 + col] = f2bf(acc[i][j][r]);
            }
}

// ---------------------------------------------------------------------------
// GEMM2: y2(fp32, into d_out) = relu(bn1(y1)) @ w2^T.
// A: y1 bf16 + folded BN (a1[k]*v + c1[k], relu) -> ds_write. B: w2b bf16.
// ---------------------------------------------------------------------------
__global__ __launch_bounds__(256) void gemm2_kernel(
    const ushort_t* __restrict__ y1, const ushort_t* __restrict__ w2b,
    const float* __restrict__ a1, const float* __restrict__ c1,
    float* __restrict__ y2)
{
    __shared__ ushort_t As[64 * 32];
    __shared__ ushort_t Bs[256 * 32];
    __shared__ float sA[256], sC[256];
    const int tid = threadIdx.x;
    sA[tid] = a1[tid]; sC[tid] = c1[tid];
    const int wave = tid >> 6, lane = tid & 63;
    const int fr = lane & 15, fq = lane >> 4;
    const int m0 = blockIdx.x * 64;
    const int sr = tid >> 2, sq = tid & 3;

    f32x4 acc[4][4];
#pragma unroll
    for (int i = 0; i < 4; ++i)
#pragma unroll
        for (int j = 0; j < 4; ++j) acc[i][j] = f32x4{0.0f, 0.0f, 0.0f, 0.0f};

    for (int kc = 0; kc < 8; ++kc) {
        const int k0 = kc * 32;
        __syncthreads();
#pragma unroll
        for (int p = 0; p < 4; ++p) {
            const ushort_t* g = w2b + (size_t)(p * 64 + sr) * 256 + k0 + sq * 8;
            __builtin_amdgcn_global_load_lds((GVoid*)g, (LVoid*)(Bs + p * 2048 + wave * 512), 16, 0, 0);
        }
        {
            ushort8 raw = *(const ushort8*)(y1 + (size_t)(m0 + sr) * 256 + k0 + sq * 8);
            ushort8 hv;
#pragma unroll
            for (int j = 0; j < 8; ++j) {
                int ch = k0 + sq * 8 + j;
                float v = bf2f(raw[j]);
                hv[j] = f2bf(fmaxf(fmaf(v, sA[ch], sC[ch]), 0.0f));
            }
            *(ushort8*)(As + tid * 8) = hv;
        }
        __syncthreads();
        bf16x8 af[4], bfr[4];
#pragma unroll
        for (int i = 0; i < 4; ++i)
            af[i] = *(const bf16x8*)(As + (i * 16 + fr) * 32 + fq * 8);
#pragma unroll
        for (int j = 0; j < 4; ++j)
            bfr[j] = *(const bf16x8*)(Bs + (wave * 64 + j * 16 + fr) * 32 + fq * 8);
#pragma unroll
        for (int i = 0; i < 4; ++i)
#pragma unroll
            for (int j = 0; j < 4; ++j)
                acc[i][j] = __builtin_amdgcn_mfma_f32_16x16x32_bf16(af[i], bfr[j], acc[i][j], 0, 0, 0);
    }
#pragma unroll
    for (int i = 0; i < 4; ++i)
#pragma unroll
        for (int j = 0; j < 4; ++j)
#pragma unroll
            for (int r = 0; r < 4; ++r) {
                int row = m0 + i * 16 + fq * 4 + r;
                int col = wave * 64 + j * 16 + fr;
                y2[(size_t)row * 256 + col] = acc[i][j][r];
            }
}

// ---------------------------------------------------------------------------
// Per-channel sum / sum-of-squares (BN training stats), fp32 atomics.
// ---------------------------------------------------------------------------
__global__ __launch_bounds__(256) void stats_bf16_kernel(
    const ushort_t* __restrict__ y, float* __restrict__ sums, float* __restrict__ sqs)
{
    const int c = threadIdx.x;
    const size_t r0 = (size_t)blockIdx.x * 128;
    float s0 = 0, s1 = 0, q0 = 0, q1 = 0;
    for (int r = 0; r < 128; r += 2) {
        float v0 = bf2f(y[(r0 + r + 0) * 256 + c]);
        float v1 = bf2f(y[(r0 + r + 1) * 256 + c]);
        s0 += v0; q0 = fmaf(v0, v0, q0);
        s1 += v1; q1 = fmaf(v1, v1, q1);
    }
    atomicAdd(&sums[c], s0 + s1);
    atomicAdd(&sqs[c], q0 + q1);
}

__global__ __launch_bounds__(256) void stats_f32_kernel(
    const float* __restrict__ y, float* __restrict__ sums, float* __restrict__ sqs)
{
    const int c = threadIdx.x;
    const size_t r0 = (size_t)blockIdx.x * 128;
    float s0 = 0, s1 = 0, q0 = 0, q1 = 0;
    for (int r = 0; r < 128; r += 2) {
        float v0 = y[(r0 + r + 0) * 256 + c];
        float v1 = y[(r0 + r + 1) * 256 + c];
        s0 += v0; q0 = fmaf(v0, v0, q0);
        s1 += v1; q1 = fmaf(v1, v1, q1);
    }
    atomicAdd(&sums[c], s0 + s1);
    atomicAdd(&sqs[c], q0 + q1);
}

__global__ __launch_bounds__(256) void finalize_kernel(
    const float* __restrict__ sums, const float* __restrict__ sqs,
    const float* __restrict__ g, const float* __restrict__ bias,
    float* __restrict__ a, float* __restrict__ c)
{
    const int ch = threadIdx.x;
    const float inv_n = 1.0f / 65536.0f;
    float mu = sums[ch] * inv_n;
    float var = fmaf(-mu, mu, sqs[ch] * inv_n);
    float is = 1.0f / sqrtf(var + 1e-5f);
    float aa = g[ch] * is;
    a[ch] = aa;
    c[ch] = fmaf(-mu, aa, bias[ch]);
}

// out = relu(a2[c]*y2 + c2[c]) in place (fp32, 4 elems/thread)
__global__ __launch_bounds__(256) void apply_kernel(
    float* __restrict__ y2, const float* __restrict__ a, const float* __restrict__ c)
{
    const size_t i = ((size_t)blockIdx.x * 256 + threadIdx.x) * 4;
    const int ch = (int)(i & 255);
    float4 v = *(const float4*)(y2 + i);
    const float4 av = *(const float4*)(a + ch);
    const float4 cv = *(const float4*)(c + ch);
    v.x = fmaxf(fmaf(v.x, av.x, cv.x), 0.0f);
    v.y = fmaxf(fmaf(v.y, av.y, cv.y), 0.0f);
    v.z = fmaxf(fmaf(v.z, av.z, cv.z), 0.0f);
    v.w = fmaxf(fmaf(v.w, av.w, cv.w), 0.0f);
    *(float4*)(y2 + i) = v;
}

extern "C" void kernel_launch(void* const* d_in, const int* in_sizes, int n_in,
                              void* d_out, int out_size, void* d_ws, size_t ws_size,
                              hipStream_t stream)
{
    const float* xyz1    = (const float*)d_in[0];
    const float* xyz2    = (const float*)d_in[1];
    const float* points1 = (const float*)d_in[2];
    const float* points2 = (const float*)d_in[3];
    const float* w1      = (const float*)d_in[4];
    const float* g1      = (const float*)d_in[5];
    const float* b1      = (const float*)d_in[6];
    const float* w2      = (const float*)d_in[7];
    const float* g2      = (const float*)d_in[8];
    const float* b2      = (const float*)d_in[9];
    float* out = (float*)d_out;

    char* ws = (char*)d_ws;
    float* sums1 = (float*)(ws + 0);
    float* sqs1  = (float*)(ws + 1024);
    float* a1    = (float*)(ws + 2048);
    float* c1    = (float*)(ws + 3072);
    float* sums2 = (float*)(ws + 4096);
    float* sqs2  = (float*)(ws + 5120);
    float* a2    = (float*)(ws + 6144);
    float* c2    = (float*)(ws + 7168);
    ushort_t* w1b = (ushort_t*)(ws + (64u << 10));    // 256 KB
    ushort_t* w2b = (ushort_t*)(ws + (320u << 10));   // 128 KB
    int*   idx   = (int*)(ws + (1u << 20));           // 768 KB
    float* wgt   = (float*)(ws + (2u << 20));         // 768 KB
    ushort_t* y1 = (ushort_t*)(ws + (4u << 20));      // 32 MB  (total ~36 MB)

    hipMemsetAsync(ws, 0, 8192, stream);  // zero BN stat accumulators
    cvt_kernel<<<dim3(512), 256, 0, stream>>>(w1, w1b, 131072);
    cvt_kernel<<<dim3(256), 256, 0, stream>>>(w2, w2b, 65536);
    knn_kernel<<<dim3(16, 16), 256, 0, stream>>>(xyz1, xyz2, idx, wgt);
    gemm1_kernel<<<dim3(1024), 256, 0, stream>>>(points1, points2, idx, wgt, w1b, y1);
    stats_bf16_kernel<<<dim3(512), 256, 0, stream>>>(y1, sums1, sqs1);
    finalize_kernel<<<dim3(1), 256, 0, stream>>>(sums1, sqs1, g1, b1, a1, c1);
    gemm2_kernel<<<dim3(1024), 256, 0, stream>>>(y1, w2b, a1, c1, out);
    stats_f32_kernel<<<dim3(512), 256, 0, stream>>>(out, sums2, sqs2);
    finalize_kernel<<<dim3(1), 256, 0, stream>>>(sums2, sqs2, g2, b2, a2, c2);
    apply_kernel<<<dim3(16384), 256, 0, stream>>>(out, a2, c2);
}

// Round 3
// 302.859 us; speedup vs baseline: 1.2511x; 1.2511x over previous
//
#include <hip/hip_runtime.h>
#include <stdint.h>

typedef unsigned short ushort_t;
typedef __bf16 bf16x8 __attribute__((ext_vector_type(8)));
typedef float f32x4 __attribute__((ext_vector_type(4)));
typedef unsigned short ushort8 __attribute__((ext_vector_type(8)));
typedef __attribute__((address_space(1))) void GVoid;
typedef __attribute__((address_space(3))) void LVoid;

#define DEV static __device__ __forceinline__

DEV unsigned short f2bf(float f) {
    union { float f; unsigned int i; } v; v.f = f;
    unsigned int u = v.i;
    return (unsigned short)((u + 0x7fffu + ((u >> 16) & 1u)) >> 16);
}
DEV float bf2f(unsigned short u) {
    union { unsigned int i; float f; } v; v.i = ((unsigned int)u) << 16; return v.f;
}

// ---------------------------------------------------------------------------
// fp32 -> bf16 weight conversion (w1: 131072 elems, w2: 65536 elems)
// ---------------------------------------------------------------------------
__global__ __launch_bounds__(256) void cvt_kernel(
    const float* __restrict__ in, ushort_t* __restrict__ out, int n)
{
    int i = blockIdx.x * 256 + threadIdx.x;
    if (i < n) out[i] = f2bf(in[i]);
}

// ---------------------------------------------------------------------------
// 3-NN v2: 4-way candidate split. Block = 64 queries x 4 chunks (wave=chunk,
// lane=query -> LDS candidate reads are wave-uniform broadcasts). Each thread
// scans 256 candidates; partial top-3s merged via LDS in chunk order with
// strict < insertion => identical stable tie-breaking to lax.top_k over 1024.
// d2 replicates the reference formula (qq + pp - 2*dot, non-FMA, same assoc).
// Grid 1024 blocks = 16 waves/CU (was 4).
// ---------------------------------------------------------------------------
__global__ __launch_bounds__(256) void knn_kernel(
    const float* __restrict__ xyz1, const float* __restrict__ xyz2,
    int* __restrict__ idx_out, float* __restrict__ w_out)
{
    __shared__ float4 P[1024];     // 16 KB: all candidates of this batch
    __shared__ float mD[12][64];   // partial top-3 dists, [chunk*3+k][query]
    __shared__ int   mI[12][64];   // partial top-3 idx
    const int b = blockIdx.y;
    const int tid = threadIdx.x;
    for (int s = tid; s < 1024; s += 256) {
        const float* p = xyz2 + ((size_t)b * 1024 + s) * 3;
        float x = p[0], y = p[1], z = p[2];
        float pp = __fadd_rn(__fadd_rn(__fmul_rn(x, x), __fmul_rn(y, y)), __fmul_rn(z, z));
        P[s] = make_float4(x, y, z, pp);
    }
    __syncthreads();
    const int ql = tid & 63;          // query lane within block
    const int chunk = tid >> 6;       // candidate chunk 0..3
    const int n = blockIdx.x * 64 + ql;
    const float* q = xyz1 + ((size_t)b * 4096 + n) * 3;
    float qx = q[0], qy = q[1], qz = q[2];
    float qq = __fadd_rn(__fadd_rn(__fmul_rn(qx, qx), __fmul_rn(qy, qy)), __fmul_rn(qz, qz));
    float d0 = 1e30f, d1 = 1e30f, d2 = 1e30f;
    int i0 = 0, i1 = 0, i2 = 0;
    const int s0 = chunk * 256;
#pragma unroll 4
    for (int s = s0; s < s0 + 256; ++s) {
        float4 p = P[s];
        float dot = __fadd_rn(__fadd_rn(__fmul_rn(qx, p.x), __fmul_rn(qy, p.y)), __fmul_rn(qz, p.z));
        float d = __fsub_rn(__fadd_rn(qq, p.w), __fmul_rn(2.0f, dot));
        if (d < d2) {                 // strict < : lowest index wins ties
            if (d < d1) {
                d2 = d1; i2 = i1;
                if (d < d0) { d1 = d0; i1 = i0; d0 = d; i0 = s; }
                else        { d1 = d;  i1 = s; }
            } else { d2 = d; i2 = s; }
        }
    }
    mD[chunk * 3 + 0][ql] = d0; mI[chunk * 3 + 0][ql] = i0;
    mD[chunk * 3 + 1][ql] = d1; mI[chunk * 3 + 1][ql] = i1;
    mD[chunk * 3 + 2][ql] = d2; mI[chunk * 3 + 2][ql] = i2;
    __syncthreads();
    if (tid < 64) {
        float e0 = 1e30f, e1 = 1e30f, e2 = 1e30f;
        int j0 = 0, j1 = 0, j2 = 0;
#pragma unroll
        for (int c = 0; c < 12; ++c) {     // chunk-major order = ascending index
            float d = mD[c][ql]; int i = mI[c][ql];
            if (d < e2) {
                if (d < e1) {
                    e2 = e1; j2 = j1;
                    if (d < e0) { e1 = e0; j1 = j0; e0 = d; j0 = i; }
                    else        { e1 = d;  j1 = i; }
                } else { e2 = d; j2 = i; }
            }
        }
        float r0 = 1.0f / (e0 + 1e-8f);
        float r1 = 1.0f / (e1 + 1e-8f);
        float r2 = 1.0f / (e2 + 1e-8f);
        float rs = __fadd_rn(__fadd_rn(r0, r1), r2);
        size_t o = ((size_t)b * 4096 + n) * 3;
        idx_out[o + 0] = j0; idx_out[o + 1] = j1; idx_out[o + 2] = j2;
        w_out[o + 0] = r0 / rs; w_out[o + 1] = r1 / rs; w_out[o + 2] = r2 / rs;
    }
}

// ---------------------------------------------------------------------------
// GEMM1: y1[65536,256] = [points1 | interp] (65536x512, fp32 virtual) @ w1^T.
// BM=64, BN=256, BK=32, 4 waves x (64x64 tile = 4x4 mfma_16x16x32_bf16).
// A-staging: kc<8 -> points1 fp32 load + cvt + ds_write;
//            kc>=8 -> 3-NN interpolation computed on the fly (gather fp32
//            rows of points2, weighted sum, cvt, ds_write).
// B-staging: w1b bf16 via global_load_lds width=16.
// ---------------------------------------------------------------------------
__global__ __launch_bounds__(256) void gemm1_kernel(
    const float* __restrict__ p1, const float* __restrict__ points2,
    const int* __restrict__ idx, const float* __restrict__ wgt,
    const ushort_t* __restrict__ w1b, ushort_t* __restrict__ y)
{
    __shared__ ushort_t As[64 * 32];    // 4 KB
    __shared__ ushort_t Bs[256 * 32];   // 16 KB
    __shared__ int   sIdx[192];
    __shared__ float sWgt[192];
    const int tid = threadIdx.x;
    const int wave = tid >> 6, lane = tid & 63;
    const int fr = lane & 15, fq = lane >> 4;
    const int m0 = blockIdx.x * 64;
    const int sr = tid >> 2, sq = tid & 3;   // staging row (tid/4), col-group (tid%4)

    if (tid < 192) { sIdx[tid] = idx[(size_t)m0 * 3 + tid]; sWgt[tid] = wgt[(size_t)m0 * 3 + tid]; }

    const float* p2base = points2 + (size_t)(m0 >> 12) * (1024 * 256);

    f32x4 acc[4][4];
#pragma unroll
    for (int i = 0; i < 4; ++i)
#pragma unroll
        for (int j = 0; j < 4; ++j) acc[i][j] = f32x4{0.0f, 0.0f, 0.0f, 0.0f};

    for (int kc = 0; kc < 16; ++kc) {
        __syncthreads();
        // B tile 256x32 bf16 via async global->LDS (dest = uniform base + lane*16)
#pragma unroll
        for (int p = 0; p < 4; ++p) {
            const ushort_t* g = w1b + (size_t)(p * 64 + sr) * 512 + kc * 32 + sq * 8;
            __builtin_amdgcn_global_load_lds((GVoid*)g, (LVoid*)(Bs + p * 2048 + wave * 512), 16, 0, 0);
        }
        // A tile 64x32: thread t -> row t>>2, cols (t&3)*8 .. +8  (== As + t*8)
        {
            const int r = sr;              // row within tile
            const int c0 = sq * 8;         // col within 32-chunk
            float v[8];
            if (kc < 8) {
                const float4* g = (const float4*)(p1 + (size_t)(m0 + r) * 256 + kc * 32 + c0);
                float4 u0 = g[0], u1 = g[1];
                v[0] = u0.x; v[1] = u0.y; v[2] = u0.z; v[3] = u0.w;
                v[4] = u1.x; v[5] = u1.y; v[6] = u1.z; v[7] = u1.w;
            } else {
                const int ka = (kc - 8) * 32 + c0;
                int i0 = sIdx[r * 3 + 0], i1 = sIdx[r * 3 + 1], i2 = sIdx[r * 3 + 2];
                float w0 = sWgt[r * 3 + 0], w1 = sWgt[r * 3 + 1], w2 = sWgt[r * 3 + 2];
                const float4* g0 = (const float4*)(p2base + (size_t)i0 * 256 + ka);
                const float4* g1 = (const float4*)(p2base + (size_t)i1 * 256 + ka);
                const float4* g2 = (const float4*)(p2base + (size_t)i2 * 256 + ka);
                float4 a0 = g0[0], a1 = g0[1];
                float4 b0 = g1[0], b1 = g1[1];
                float4 c0v = g2[0], c1v = g2[1];
                v[0] = fmaf(w2, c0v.x, fmaf(w1, b0.x, __fmul_rn(w0, a0.x)));
                v[1] = fmaf(w2, c0v.y, fmaf(w1, b0.y, __fmul_rn(w0, a0.y)));
                v[2] = fmaf(w2, c0v.z, fmaf(w1, b0.z, __fmul_rn(w0, a0.z)));
                v[3] = fmaf(w2, c0v.w, fmaf(w1, b0.w, __fmul_rn(w0, a0.w)));
                v[4] = fmaf(w2, c1v.x, fmaf(w1, b1.x, __fmul_rn(w0, a1.x)));
                v[5] = fmaf(w2, c1v.y, fmaf(w1, b1.y, __fmul_rn(w0, a1.y)));
                v[6] = fmaf(w2, c1v.z, fmaf(w1, b1.z, __fmul_rn(w0, a1.z)));
                v[7] = fmaf(w2, c1v.w, fmaf(w1, b1.w, __fmul_rn(w0, a1.w)));
            }
            ushort8 hv;
#pragma unroll
            for (int j = 0; j < 8; ++j) hv[j] = f2bf(v[j]);
            *(ushort8*)(As + tid * 8) = hv;
        }
        __syncthreads();
        bf16x8 af[4], bfr[4];
#pragma unroll
        for (int i = 0; i < 4; ++i)
            af[i] = *(const bf16x8*)(As + (i * 16 + fr) * 32 + fq * 8);
#pragma unroll
        for (int j = 0; j < 4; ++j)
            bfr[j] = *(const bf16x8*)(Bs + (wave * 64 + j * 16 + fr) * 32 + fq * 8);
#pragma unroll
        for (int i = 0; i < 4; ++i)
#pragma unroll
            for (int j = 0; j < 4; ++j)
                acc[i][j] = __builtin_amdgcn_mfma_f32_16x16x32_bf16(af[i], bfr[j], acc[i][j], 0, 0, 0);
    }
#pragma unroll
    for (int i = 0; i < 4; ++i)
#pragma unroll
        for (int j = 0; j < 4; ++j)
#pragma unroll
            for (int r = 0; r < 4; ++r) {
                int row = m0 + i * 16 + fq * 4 + r;       // C/D: row=(lane>>4)*4+reg
                int col = wave * 64 + j * 16 + fr;        //      col=lane&15
                y[(size_t)row * 256 + col] = f2bf(acc[i][j][r]);
            }
}

// ---------------------------------------------------------------------------
// GEMM2: y2(fp32, into d_out) = relu(bn1(y1)) @ w2^T.
// A: y1 bf16 + folded BN (a1[k]*v + c1[k], relu) -> ds_write. B: w2b bf16.
// ---------------------------------------------------------------------------
__global__ __launch_bounds__(256) void gemm2_kernel(
    const ushort_t* __restrict__ y1, const ushort_t* __restrict__ w2b,
    const float* __restrict__ a1, const float* __restrict__ c1,
    float* __restrict__ y2)
{
    __shared__ ushort_t As[64 * 32];
    __shared__ ushort_t Bs[256 * 32];
    __shared__ float sA[256], sC[256];
    const int tid = threadIdx.x;
    sA[tid] = a1[tid]; sC[tid] = c1[tid];
    const int wave = tid >> 6, lane = tid & 63;
    const int fr = lane & 15, fq = lane >> 4;
    const int m0 = blockIdx.x * 64;
    const int sr = tid >> 2, sq = tid & 3;

    f32x4 acc[4][4];
#pragma unroll
    for (int i = 0; i < 4; ++i)
#pragma unroll
        for (int j = 0; j < 4; ++j) acc[i][j] = f32x4{0.0f, 0.0f, 0.0f, 0.0f};

    for (int kc = 0; kc < 8; ++kc) {
        const int k0 = kc * 32;
        __syncthreads();
#pragma unroll
        for (int p = 0; p < 4; ++p) {
            const ushort_t* g = w2b + (size_t)(p * 64 + sr) * 256 + k0 + sq * 8;
            __builtin_amdgcn_global_load_lds((GVoid*)g, (LVoid*)(Bs + p * 2048 + wave * 512), 16, 0, 0);
        }
        {
            ushort8 raw = *(const ushort8*)(y1 + (size_t)(m0 + sr) * 256 + k0 + sq * 8);
            ushort8 hv;
#pragma unroll
            for (int j = 0; j < 8; ++j) {
                int ch = k0 + sq * 8 + j;
                float v = bf2f(raw[j]);
                hv[j] = f2bf(fmaxf(fmaf(v, sA[ch], sC[ch]), 0.0f));
            }
            *(ushort8*)(As + tid * 8) = hv;
        }
        __syncthreads();
        bf16x8 af[4], bfr[4];
#pragma unroll
        for (int i = 0; i < 4; ++i)
            af[i] = *(const bf16x8*)(As + (i * 16 + fr) * 32 + fq * 8);
#pragma unroll
        for (int j = 0; j < 4; ++j)
            bfr[j] = *(const bf16x8*)(Bs + (wave * 64 + j * 16 + fr) * 32 + fq * 8);
#pragma unroll
        for (int i = 0; i < 4; ++i)
#pragma unroll
            for (int j = 0; j < 4; ++j)
                acc[i][j] = __builtin_amdgcn_mfma_f32_16x16x32_bf16(af[i], bfr[j], acc[i][j], 0, 0, 0);
    }
#pragma unroll
    for (int i = 0; i < 4; ++i)
#pragma unroll
        for (int j = 0; j < 4; ++j)
#pragma unroll
            for (int r = 0; r < 4; ++r) {
                int row = m0 + i * 16 + fq * 4 + r;
                int col = wave * 64 + j * 16 + fr;
                y2[(size_t)row * 256 + col] = acc[i][j][r];
            }
}

// ---------------------------------------------------------------------------
// Per-channel sum / sum-of-squares (BN training stats), fp32 atomics.
// ---------------------------------------------------------------------------
__global__ __launch_bounds__(256) void stats_bf16_kernel(
    const ushort_t* __restrict__ y, float* __restrict__ sums, float* __restrict__ sqs)
{
    const int c = threadIdx.x;
    const size_t r0 = (size_t)blockIdx.x * 128;
    float s0 = 0, s1 = 0, q0 = 0, q1 = 0;
    for (int r = 0; r < 128; r += 2) {
        float v0 = bf2f(y[(r0 + r + 0) * 256 + c]);
        float v1 = bf2f(y[(r0 + r + 1) * 256 + c]);
        s0 += v0; q0 = fmaf(v0, v0, q0);
        s1 += v1; q1 = fmaf(v1, v1, q1);
    }
    atomicAdd(&sums[c], s0 + s1);
    atomicAdd(&sqs[c], q0 + q1);
}

__global__ __launch_bounds__(256) void stats_f32_kernel(
    const float* __restrict__ y, float* __restrict__ sums, float* __restrict__ sqs)
{
    const int c = threadIdx.x;
    const size_t r0 = (size_t)blockIdx.x * 128;
    float s0 = 0, s1 = 0, q0 = 0, q1 = 0;
    for (int r = 0; r < 128; r += 2) {
        float v0 = y[(r0 + r + 0) * 256 + c];
        float v1 = y[(r0 + r + 1) * 256 + c];
        s0 += v0; q0 = fmaf(v0, v0, q0);
        s1 += v1; q1 = fmaf(v1, v1, q1);
    }
    atomicAdd(&sums[c], s0 + s1);
    atomicAdd(&sqs[c], q0 + q1);
}

__global__ __launch_bounds__(256) void finalize_kernel(
    const float* __restrict__ sums, const float* __restrict__ sqs,
    const float* __restrict__ g, const float* __restrict__ bias,
    float* __restrict__ a, float* __restrict__ c)
{
    const int ch = threadIdx.x;
    const float inv_n = 1.0f / 65536.0f;
    float mu = sums[ch] * inv_n;
    float var = fmaf(-mu, mu, sqs[ch] * inv_n);
    float is = 1.0f / sqrtf(var + 1e-5f);
    float aa = g[ch] * is;
    a[ch] = aa;
    c[ch] = fmaf(-mu, aa, bias[ch]);
}

// out = relu(a2[c]*y2 + c2[c]) in place (fp32, 4 elems/thread)
__global__ __launch_bounds__(256) void apply_kernel(
    float* __restrict__ y2, const float* __restrict__ a, const float* __restrict__ c)
{
    const size_t i = ((size_t)blockIdx.x * 256 + threadIdx.x) * 4;
    const int ch = (int)(i & 255);
    float4 v = *(const float4*)(y2 + i);
    const float4 av = *(const float4*)(a + ch);
    const float4 cv = *(const float4*)(c + ch);
    v.x = fmaxf(fmaf(v.x, av.x, cv.x), 0.0f);
    v.y = fmaxf(fmaf(v.y, av.y, cv.y), 0.0f);
    v.z = fmaxf(fmaf(v.z, av.z, cv.z), 0.0f);
    v.w = fmaxf(fmaf(v.w, av.w, cv.w), 0.0f);
    *(float4*)(y2 + i) = v;
}

extern "C" void kernel_launch(void* const* d_in, const int* in_sizes, int n_in,
                              void* d_out, int out_size, void* d_ws, size_t ws_size,
                              hipStream_t stream)
{
    const float* xyz1    = (const float*)d_in[0];
    const float* xyz2    = (const float*)d_in[1];
    const float* points1 = (const float*)d_in[2];
    const float* points2 = (const float*)d_in[3];
    const float* w1      = (const float*)d_in[4];
    const float* g1      = (const float*)d_in[5];
    const float* b1      = (const float*)d_in[6];
    const float* w2      = (const float*)d_in[7];
    const float* g2      = (const float*)d_in[8];
    const float* b2      = (const float*)d_in[9];
    float* out = (float*)d_out;

    char* ws = (char*)d_ws;
    float* sums1 = (float*)(ws + 0);
    float* sqs1  = (float*)(ws + 1024);
    float* a1    = (float*)(ws + 2048);
    float* c1    = (float*)(ws + 3072);
    float* sums2 = (float*)(ws + 4096);
    float* sqs2  = (float*)(ws + 5120);
    float* a2    = (float*)(ws + 6144);
    float* c2    = (float*)(ws + 7168);
    ushort_t* w1b = (ushort_t*)(ws + (64u << 10));    // 256 KB
    ushort_t* w2b = (ushort_t*)(ws + (320u << 10));   // 128 KB
    int*   idx   = (int*)(ws + (1u << 20));           // 768 KB
    float* wgt   = (float*)(ws + (2u << 20));         // 768 KB
    ushort_t* y1 = (ushort_t*)(ws + (4u << 20));      // 32 MB  (total ~36 MB)

    hipMemsetAsync(ws, 0, 8192, stream);  // zero BN stat accumulators
    cvt_kernel<<<dim3(512), 256, 0, stream>>>(w1, w1b, 131072);
    cvt_kernel<<<dim3(256), 256, 0, stream>>>(w2, w2b, 65536);
    knn_kernel<<<dim3(64, 16), 256, 0, stream>>>(xyz1, xyz2, idx, wgt);
    gemm1_kernel<<<dim3(1024), 256, 0, stream>>>(points1, points2, idx, wgt, w1b, y1);
    stats_bf16_kernel<<<dim3(512), 256, 0, stream>>>(y1, sums1, sqs1);
    finalize_kernel<<<dim3(1), 256, 0, stream>>>(sums1, sqs1, g1, b1, a1, c1);
    gemm2_kernel<<<dim3(1024), 256, 0, stream>>>(y1, w2b, a1, c1, out);
    stats_f32_kernel<<<dim3(512), 256, 0, stream>>>(out, sums2, sqs2);
    finalize_kernel<<<dim3(1), 256, 0, stream>>>(sums2, sqs2, g2, b2, a2, c2);
    apply_kernel<<<dim3(16384), 256, 0, stream>>>(out, a2, c2);
}